// Round 1
// baseline (1554.873 us; speedup 1.0000x reference)
//
#include <hip/hip_runtime.h>

#define NN 50000
#define NE 1600000
#define DF 64
#define DO_ 128
#define KD 192      // 3*DF (edge MLP) == DF+DO_ (node MLP)
#define LDSTR 200   // padded LDS row stride (bf16 elems); 200*4B%32banks -> 2-way (free)

typedef __attribute__((ext_vector_type(8))) short short8;
typedef __attribute__((ext_vector_type(4))) float floatx4;

__device__ inline ushort f2bf(float f) {
  union { float f; unsigned u; } v; v.f = f;
  unsigned u = v.u;
  unsigned r = (u + 0x7fffu + ((u >> 16) & 1u)) >> 16;  // RNE
  return (ushort)r;
}

// ---- prep: nodes fp32->bf16; W_edge/W_node -> transposed bf16 [n][k] ----
__global__ __launch_bounds__(256)
void prep_kernel(const float* __restrict__ nodes,
                 const float* __restrict__ W_edge,
                 const float* __restrict__ W_node,
                 ushort* __restrict__ nodes_bf,
                 ushort* __restrict__ We_t,
                 ushort* __restrict__ Wn_t) {
  int bid = blockIdx.x, tid = threadIdx.x;
  if (bid < 3125) {                       // 3125*256*4 == 50000*64 exactly
    int i = bid * 256 + tid;              // float4 index
    float4 v = ((const float4*)nodes)[i];
    ushort4 o; o.x = f2bf(v.x); o.y = f2bf(v.y); o.z = f2bf(v.z); o.w = f2bf(v.w);
    *(ushort4*)(nodes_bf + (size_t)i * 4) = o;
  } else {                                // 192 blocks * 256 == 2*24576 exactly
    int idx = (bid - 3125) * 256 + tid;   // 0..49151
    const float* W = (idx < 24576) ? W_edge : W_node;
    ushort* Wt     = (idx < 24576) ? We_t  : Wn_t;
    int j = (idx < 24576) ? idx : idx - 24576;
    int k = j >> 7;          // 0..191 (row of W: [192][128])
    int n = j & 127;         // 0..127
    Wt[n * KD + k] = f2bf(W[k * DO_ + n]);
  }
}

// ---- edge MLP + fused atomic scatter into received ----
__global__ __launch_bounds__(256, 2)
void edge_kernel(const float* __restrict__ edges,
                 const ushort* __restrict__ nodes_bf,
                 const int* __restrict__ senders,
                 const int* __restrict__ receivers,
                 const ushort* __restrict__ We_t,   // [128][192] bf16
                 const float* __restrict__ b_edge,
                 float* __restrict__ new_edges,     // [NE][128]
                 float* __restrict__ received) {    // [NN][128] fp32, pre-zeroed
  __shared__ ushort lds_a[128 * LDSTR];
  __shared__ int lds_sr[256];            // [0:128) senders, [128:256) receivers
  const int tid = threadIdx.x;
  const int e0 = blockIdx.x * 128;

  if (tid < 128) lds_sr[tid] = senders[e0 + tid];
  else           lds_sr[tid] = receivers[e0 + tid - 128];
  __syncthreads();

  // edges (fp32) -> LDS cols [0,64)
  {
    const float4* e4 = (const float4*)edges + (size_t)e0 * 16;
    #pragma unroll
    for (int i = 0; i < 8; ++i) {
      int idx = i * 256 + tid;           // 0..2047
      int row = idx >> 4, c4 = idx & 15;
      float4 v = e4[idx];
      ushort4 o; o.x = f2bf(v.x); o.y = f2bf(v.y); o.z = f2bf(v.z); o.w = f2bf(v.w);
      *(ushort4*)(&lds_a[row * LDSTR + c4 * 4]) = o;
    }
  }
  // gathered sender/receiver node feats (bf16) -> LDS cols [64,192)
  #pragma unroll
  for (int i = 0; i < 8; ++i) {
    int idx = i * 256 + tid;             // 0..2047
    int row = idx >> 4, p = idx & 15;
    int s = p >> 3, off = p & 7;         // s: 0=sender 1=receiver; off: 16B piece
    int src = lds_sr[s * 128 + row];
    uint4 v = *(const uint4*)(nodes_bf + (size_t)src * 64 + off * 8);
    *(uint4*)(&lds_a[row * LDSTR + 64 + s * 64 + off * 8]) = v;
  }
  __syncthreads();

  const int wave = tid >> 6, lane = tid & 63;
  const int quad = lane >> 4, col = lane & 15;

  // B fragments held in registers: B[k=quad*8+j][n=lane&15], n-major storage
  short8 bfrag[6][2];
  #pragma unroll
  for (int ks = 0; ks < 6; ++ks)
    #pragma unroll
    for (int nt = 0; nt < 2; ++nt) {
      int n = wave * 32 + nt * 16 + col;
      bfrag[ks][nt] = *(const short8*)(We_t + n * KD + ks * 32 + quad * 8);
    }

  floatx4 acc[8][2];
  #pragma unroll
  for (int m = 0; m < 8; ++m)
    #pragma unroll
    for (int nt = 0; nt < 2; ++nt) acc[m][nt] = (floatx4)(0.0f);

  #pragma unroll
  for (int ks = 0; ks < 6; ++ks) {
    #pragma unroll
    for (int m = 0; m < 8; ++m) {
      short8 a = *(const short8*)(&lds_a[(m * 16 + col) * LDSTR + ks * 32 + quad * 8]);
      acc[m][0] = __builtin_amdgcn_mfma_f32_16x16x32_bf16(a, bfrag[ks][0], acc[m][0], 0, 0, 0);
      acc[m][1] = __builtin_amdgcn_mfma_f32_16x16x32_bf16(a, bfrag[ks][1], acc[m][1], 0, 0, 0);
    }
  }

  float bias0 = b_edge[wave * 32 + col];
  float bias1 = b_edge[wave * 32 + 16 + col];
  #pragma unroll
  for (int m = 0; m < 8; ++m) {
    #pragma unroll
    for (int nt = 0; nt < 2; ++nt) {
      int n = wave * 32 + nt * 16 + col;
      float bs = nt ? bias1 : bias0;
      #pragma unroll
      for (int r = 0; r < 4; ++r) {
        int row = m * 16 + quad * 4 + r;
        float v = acc[m][nt][r] + bs;
        v = v > 0.0f ? v : 0.0f;
        new_edges[(size_t)(e0 + row) * 128 + n] = v;
        int rcv = lds_sr[128 + row];
        unsafeAtomicAdd(&received[(size_t)rcv * 128 + n], v);
      }
    }
  }
}

// ---- node MLP: A = [nodes_bf16 | received->bf16] ----
__global__ __launch_bounds__(256, 2)
void node_kernel(const ushort* __restrict__ nodes_bf,
                 const float* __restrict__ received,
                 const ushort* __restrict__ Wn_t,   // [128][192] bf16
                 const float* __restrict__ b_node,
                 float* __restrict__ new_nodes) {   // [NN][128]
  __shared__ ushort lds_a[128 * LDSTR];
  const int tid = threadIdx.x;
  const int n0 = blockIdx.x * 128;

  // nodes bf16 -> cols [0,64): 128 rows x 8 x 16B pieces
  #pragma unroll
  for (int i = 0; i < 4; ++i) {
    int idx = i * 256 + tid;             // 0..1023
    int row = idx >> 3, off = idx & 7;
    int src = n0 + row; if (src >= NN) src = 0;
    uint4 v = *(const uint4*)(nodes_bf + (size_t)src * 64 + off * 8);
    *(uint4*)(&lds_a[row * LDSTR + off * 8]) = v;
  }
  // received fp32 -> bf16 cols [64,192): 128 rows x 32 float4 pieces
  #pragma unroll
  for (int i = 0; i < 16; ++i) {
    int idx = i * 256 + tid;             // 0..4095
    int row = idx >> 5, c4 = idx & 31;
    int src = n0 + row; if (src >= NN) src = 0;
    float4 v = *(const float4*)(received + (size_t)src * 128 + c4 * 4);
    ushort4 o; o.x = f2bf(v.x); o.y = f2bf(v.y); o.z = f2bf(v.z); o.w = f2bf(v.w);
    *(ushort4*)(&lds_a[row * LDSTR + 64 + c4 * 4]) = o;
  }
  __syncthreads();

  const int wave = tid >> 6, lane = tid & 63;
  const int quad = lane >> 4, col = lane & 15;

  short8 bfrag[6][2];
  #pragma unroll
  for (int ks = 0; ks < 6; ++ks)
    #pragma unroll
    for (int nt = 0; nt < 2; ++nt) {
      int n = wave * 32 + nt * 16 + col;
      bfrag[ks][nt] = *(const short8*)(Wn_t + n * KD + ks * 32 + quad * 8);
    }

  floatx4 acc[8][2];
  #pragma unroll
  for (int m = 0; m < 8; ++m)
    #pragma unroll
    for (int nt = 0; nt < 2; ++nt) acc[m][nt] = (floatx4)(0.0f);

  #pragma unroll
  for (int ks = 0; ks < 6; ++ks) {
    #pragma unroll
    for (int m = 0; m < 8; ++m) {
      short8 a = *(const short8*)(&lds_a[(m * 16 + col) * LDSTR + ks * 32 + quad * 8]);
      acc[m][0] = __builtin_amdgcn_mfma_f32_16x16x32_bf16(a, bfrag[ks][0], acc[m][0], 0, 0, 0);
      acc[m][1] = __builtin_amdgcn_mfma_f32_16x16x32_bf16(a, bfrag[ks][1], acc[m][1], 0, 0, 0);
    }
  }

  float bias0 = b_node[wave * 32 + col];
  float bias1 = b_node[wave * 32 + 16 + col];
  #pragma unroll
  for (int m = 0; m < 8; ++m) {
    #pragma unroll
    for (int nt = 0; nt < 2; ++nt) {
      int n = wave * 32 + nt * 16 + col;
      float bs = nt ? bias1 : bias0;
      #pragma unroll
      for (int r = 0; r < 4; ++r) {
        int row = m * 16 + quad * 4 + r;
        int nrow = n0 + row;
        if (nrow < NN) {
          float v = acc[m][nt][r] + bs;
          v = v > 0.0f ? v : 0.0f;
          new_nodes[(size_t)nrow * 128 + n] = v;
        }
      }
    }
  }
}

extern "C" void kernel_launch(void* const* d_in, const int* in_sizes, int n_in,
                              void* d_out, int out_size, void* d_ws, size_t ws_size,
                              hipStream_t stream) {
  const float* nodes     = (const float*)d_in[0];
  const float* edges     = (const float*)d_in[1];
  const int*   senders   = (const int*)d_in[2];
  const int*   receivers = (const int*)d_in[3];
  const float* W_edge    = (const float*)d_in[4];
  const float* b_edge    = (const float*)d_in[5];
  const float* W_node    = (const float*)d_in[6];
  const float* b_node    = (const float*)d_in[7];

  float* out       = (float*)d_out;
  float* new_nodes = out;                          // [NN*128] first (return order)
  float* new_edges = out + (size_t)NN * DO_;       // [NE*128]

  char* ws = (char*)d_ws;
  ushort* nodes_bf = (ushort*)ws;                              // 6,400,000 B
  ushort* We_t     = (ushort*)(ws + 6400000);                  // 49,152 B
  ushort* Wn_t     = (ushort*)(ws + 6400000 + 49152);          // 49,152 B
  float*  received = (float*)(ws + 6400000 + 2 * 49152);       // 25,600,000 B

  hipMemsetAsync(received, 0, (size_t)NN * DO_ * sizeof(float), stream);
  prep_kernel<<<3125 + 192, 256, 0, stream>>>(nodes, W_edge, W_node, nodes_bf, We_t, Wn_t);
  edge_kernel<<<NE / 128, 256, 0, stream>>>(edges, nodes_bf, senders, receivers,
                                            We_t, b_edge, new_edges, received);
  node_kernel<<<(NN + 127) / 128, 256, 0, stream>>>(nodes_bf, received, Wn_t, b_node, new_nodes);
}